// Round 13
// baseline (265.324 us; speedup 1.0000x reference)
//
#include <hip/hip_runtime.h>
#include <math.h>

typedef unsigned int u32;
typedef unsigned short u16;
typedef __attribute__((ext_vector_type(8))) short short8;   // 8 bf16 in 4 VGPRs
typedef __attribute__((ext_vector_type(4))) float f32x4;
typedef __attribute__((ext_vector_type(2))) u32 u32x2;

#define NN 256
#define CC 128
#define EPSV 1e-5f
#define LOG2E 1.44269504088896f
#define QSCL (0.17677669529663687f * 1.44269504088896f)   // 1/sqrt(32) * log2(e)
#define NEGBIG -1e30f

#define MFMA(a,b,c) __builtin_amdgcn_mfma_f32_16x16x32_bf16(a,b,c,0,0,0)
#define EXP2(x) __builtin_amdgcn_exp2f(x)

__device__ __forceinline__ float b2f(u16 u){ return __uint_as_float(((u32)u)<<16); }
__device__ __forceinline__ u16 f2b(float f){
  u32 x = __float_as_uint(f);
  return (u16)((x + 0x7fffu + ((x>>16)&1u)) >> 16);
}
__device__ __forceinline__ void unpk(u32 u, float&a, float&b){
  a = __uint_as_float(u<<16); b = __uint_as_float(u & 0xffff0000u);
}
__device__ __forceinline__ u32 cvtpk(float lo, float hi){
  u32 r;
  asm("v_cvt_pk_bf16_f32 %0, %1, %2" : "=v"(r) : "v"(lo), "v"(hi));
  return r;
}
__device__ __forceinline__ void gload16(const void* g, void* l){
  __builtin_amdgcn_global_load_lds((const __attribute__((address_space(1))) u32*)g,
                                   (__attribute__((address_space(3))) u32*)l, 16, 0, 0);
}

// redistribute 8 values (2 f32x4 tiles, idx = tile*16 + l4*4 + v at col l15) into
// A/B-frag short8 (lane l4 gets idx l4*8..l4*8+7 for its l15). Verified P-path algebra.
__device__ __forceinline__ short8 redist(f32x4 t0, f32x4 t1, int l4){
  u32 A0 = cvtpk(t0[0], t0[1]), A1 = cvtpk(t0[2], t0[3]);
  u32 B0 = cvtpk(t1[0], t1[1]), B1 = cvtpk(t1[2], t1[3]);
  asm volatile("v_permlane32_swap_b32 %0, %1" : "+v"(A0), "+v"(B0));
  asm volatile("v_permlane32_swap_b32 %0, %1" : "+v"(A1), "+v"(B1));
  u32 sA0 = __shfl_xor(A0, 16), sA1 = __shfl_xor(A1, 16);
  u32 sB0 = __shfl_xor(B0, 16), sB1 = __shfl_xor(B1, 16);
  bool eg = ((l4 & 1) == 0);
  union { u32 u[4]; short8 s; } pu;
  pu.u[0] = eg ? A0 : sB0;
  pu.u[1] = eg ? A1 : sB1;
  pu.u[2] = eg ? sA0 : B0;
  pu.u[3] = eg ? sA1 : B1;
  return pu.s;
}

// ---- LDS layout (bytes) ----
#define XS_OFF   0        // bf16 X[256][128] swizzled (wave-private rows) (65536)
#define WT_OFF   65536    // bf16 Wt[96][128] head slice, swizzled      (24576)
#define WO_OFF   90112    // bf16 Woh dbuf [2][128][40]                 (20480)
#define KB_OFF   110592   // bf16 K[256][40]                            (20480)
#define VT_OFF   131072   // bf16 Vt[32][264]                           (16896)
#define SV_OFF   147968   // f32 sv[128]                                (512)
#define GB_OFF   148480   // f32 g[128], b[128], bo[128]                (1536)
#define BQ_OFF   150016   // f32 bqkv[384]                              (1536)
#define RS_OFF   151552   // f32 red[16][128] (phase-0 scratch)         (8192)
#define SMEM_BYTES 159744

#define XBYTE(r,c) ((r)*256 + (((((c)>>3)) ^ ((r)&7))<<4) + ((c)&7)*2)

// ws layout (bytes)
#define WS_B0   0          // bias img phase0 (131072)
#define WS_B1   131072     // bias img phase1 (131072)
#define WS_W0   262144     // W img stage0 (139264 = 4 heads x (24576 WT + 10240 WO))
#define WS_W1   401408     // W img stage1 (139264)
#define WS_SIN  540672     // s_in f32 (131072)
#define WS_NEED 671744

// bias image, per-lane-consumed layout: u16 addr = q*256 + l4*64 + ch*8 + kt*4 + v
__global__ void prep_bias(const int* __restrict__ mask, const float* __restrict__ dist,
                          const float* __restrict__ rd, const float* __restrict__ cd,
                          u16* __restrict__ b0, u16* __restrict__ b1){
  int q = blockIdx.x, k = threadIdx.x;
  int l4 = (k >> 2) & 3, v = k & 3, kt = (k >> 4) & 1, ch = k >> 5;
  int addr = q*256 + l4*64 + ch*8 + kt*4 + v;
  float dv = dist[q*NN + k];
  b0[addr] = mask[q*NN + k] ? f2b(NEGBIG) : f2b(rd[0]*LOG2E*dv);
  b1[addr] = mask[k*NN + q] ? f2b(NEGBIG) : f2b(cd[0]*LOG2E*dv);
}

// weight images: byte-exact copies of the LDS layouts (WT swizzled, WO padded)
__global__ void prep_wimg(const float* __restrict__ rWqkv, const float* __restrict__ rWo,
                          const float* __restrict__ cWqkv, const float* __restrict__ cWo,
                          u16* __restrict__ img0, u16* __restrict__ img1){
  int h = blockIdx.x & 3, s = blockIdx.x >> 2;
  const float* Wq = s ? cWqkv : rWqkv;
  const float* Wom = s ? cWo : rWo;
  char* base = (char*)(s ? img1 : img0) + h*34816;
  for (int e = threadIdx.x; e < 96*128; e += 256){
    int t = e >> 7, c = e & 127;
    int col = (t < 32) ? (h*32 + t) : (t < 64) ? (CC + h*32 + (t-32)) : (2*CC + h*32 + (t-64));
    *(u16*)(base + t*256 + ((((c>>3) ^ (t&7)))<<4) + (c&7)*2) = f2b(Wq[c*384 + col]);
  }
  for (int e = threadIdx.x; e < 128*40; e += 256){
    int o = e / 40, d = e - o*40;
    *(u16*)(base + 24576 + (o*40 + d)*2) = (d < 32) ? f2b(Wom[(h*32 + d)*128 + o]) : (u16)0;
  }
}

template<int PHASE, int WSOK>
__launch_bounds__(1024)
__global__ void stage_kernel(const float* __restrict__ pin, const float* __restrict__ colmat,
                             const float* __restrict__ singlerow,
                             const int* __restrict__ mask, const float* __restrict__ dist,
                             const u16* __restrict__ biasimg,
                             const u16* __restrict__ wimg,
                             const float* __restrict__ Wqkv, const float* __restrict__ bqkv,
                             const float* __restrict__ Wo, const float* __restrict__ bo,
                             const float* __restrict__ dscale,
                             const float* __restrict__ lng, const float* __restrict__ lnb,
                             float* __restrict__ outp)
{
  extern __shared__ char smem[];
  char* Xs  = smem + XS_OFF;
  char* WTs = smem + WT_OFF;
  char* WOs = smem + WO_OFF;
  char* KBs = smem + KB_OFF;
  char* VTs = smem + VT_OFF;
  float* SVs = (float*)(smem + SV_OFF);
  float* GBs = (float*)(smem + GB_OFF);
  float* BQs = (float*)(smem + BQ_OFF);
  float* RSs = (float*)(smem + RS_OFF);

  const int i = blockIdx.x;
  const int tid = threadIdx.x;
  const int lid = tid & 63;
  const int w = tid >> 6;            // 16 waves; wave owns query rows w*16..w*16+15
  const int l15 = lid & 15;
  const int l4  = lid >> 4;
  const int h32 = lid >> 5;
  const int c4  = (lid & 31) * 4;
  const float* prow = pin + (size_t)i*NN*CC;
  float* orow = outp + (size_t)i*NN*CC;
  const int qglob = w*16 + l15;
  const float dsc = dscale[0] * LOG2E;

  // issue W(head 0) staging immediately (lands during LN phase)
  if (WSOK){
    const char* wb = (const char*)wimg;
    gload16(wb + tid*16, WTs + tid*16);
    if (tid < 512) gload16(wb + 16384 + tid*16, WTs + 16384 + tid*16);
    if (tid < 640) gload16(wb + 24576 + tid*16, WOs + tid*16);
  }
  if (tid < 128){ GBs[tid] = lng[tid]; GBs[128+tid] = lnb[tid]; GBs[256+tid] = bo[tid]; }
  if (tid >= 512 && tid < 896) BQs[tid-512] = bqkv[tid-512];

  // ---- LN1 -> X (bf16 swizzled); phase 0 fuses the s_out prefix ----
  if (PHASE == 0){
    f32x4 svp = {0.f,0.f,0.f,0.f};
    #pragma unroll 4
    for (int p = 0; p < 8; ++p){
      int r = w*16 + p*2 + h32;
      f32x4 pr4 = *(const f32x4*)(prow + r*CC + c4);
      f32x4 sg4 = *(const f32x4*)(colmat + r*CC + c4);
      f32x4 t = pr4 + sg4;
      u32x2 pk2; pk2.x = cvtpk(t[0], t[1]); pk2.y = cvtpk(t[2], t[3]);
      *(u32x2*)(Xs + XBYTE(r, c4)) = pk2;
      if (r < i) svp += pr4;
    }
    #pragma unroll
    for (int q = 0; q < 4; ++q) svp[q] += __shfl_xor(svp[q], 32);
    if (h32 == 0) *(f32x4*)(RSs + w*128 + c4) = svp;
    __syncthreads();
    if (tid < 128){
      float s = 0.f;
      #pragma unroll
      for (int ww = 0; ww < 16; ++ww) s += RSs[ww*128 + tid];
      SVs[tid] = s;
    }
    __syncthreads();
    f32x4 sv4 = *(const f32x4*)(SVs + c4);
    f32x4 g4  = *(const f32x4*)(GBs + c4);
    f32x4 b4  = *(const f32x4*)(GBs + 128 + c4);
    #pragma unroll 2
    for (int p = 0; p < 8; ++p){
      int r = w*16 + p*2 + h32;
      u32x2 st = *(const u32x2*)(Xs + XBYTE(r, c4));
      float t0,t1,t2,t3;
      unpk(st.x, t0, t1); unpk(st.y, t2, t3);
      t0 += sv4[0]; t1 += sv4[1]; t2 += sv4[2]; t3 += sv4[3];
      float s = (t0+t1)+(t2+t3);
      float q2 = (t0*t0+t1*t1)+(t2*t2+t3*t3);
      #pragma unroll
      for (int ms = 1; ms < 32; ms <<= 1){ s += __shfl_xor(s, ms); q2 += __shfl_xor(q2, ms); }
      float mean = s*(1.f/CC);
      float var  = fmaxf(q2*(1.f/CC) - mean*mean, 0.f);
      float rstd = rsqrtf(var + EPSV);
      float y0 = (t0-mean)*rstd*g4[0] + b4[0];
      float y1 = (t1-mean)*rstd*g4[1] + b4[1];
      float y2 = (t2-mean)*rstd*g4[2] + b4[2];
      float y3 = (t3-mean)*rstd*g4[3] + b4[3];
      u32x2 pk2; pk2.x = cvtpk(y0, y1); pk2.y = cvtpk(y2, y3);
      *(u32x2*)(Xs + XBYTE(r, c4)) = pk2;
    }
  } else {
    if (tid < 128) SVs[tid] = singlerow[i*CC + tid];
    __syncthreads();
    f32x4 sv4 = *(const f32x4*)(SVs + c4);
    f32x4 g4  = *(const f32x4*)(GBs + c4);
    f32x4 b4  = *(const f32x4*)(GBs + 128 + c4);
    #pragma unroll 4
    for (int p = 0; p < 8; ++p){
      int r = w*16 + p*2 + h32;
      f32x4 pr4 = *(const f32x4*)(prow + r*CC + c4);
      f32x4 cm4 = *(const f32x4*)(colmat + r*CC + c4);
      float t0 = pr4[0]+cm4[0]+sv4[0], t1 = pr4[1]+cm4[1]+sv4[1];
      float t2 = pr4[2]+cm4[2]+sv4[2], t3 = pr4[3]+cm4[3]+sv4[3];
      float s = (t0+t1)+(t2+t3);
      float q2 = (t0*t0+t1*t1)+(t2*t2+t3*t3);
      #pragma unroll
      for (int ms = 1; ms < 32; ms <<= 1){ s += __shfl_xor(s, ms); q2 += __shfl_xor(q2, ms); }
      float mean = s*(1.f/CC);
      float var  = fmaxf(q2*(1.f/CC) - mean*mean, 0.f);
      float rstd = rsqrtf(var + EPSV);
      float y0 = (t0-mean)*rstd*g4[0] + b4[0];
      float y1 = (t1-mean)*rstd*g4[1] + b4[1];
      float y2 = (t2-mean)*rstd*g4[2] + b4[2];
      float y3 = (t3-mean)*rstd*g4[3] + b4[3];
      u32x2 pk2; pk2.x = cvtpk(y0, y1); pk2.y = cvtpk(y2, y3);
      *(u32x2*)(Xs + XBYTE(r, c4)) = pk2;
    }
  }
  if (WSOK) asm volatile("s_waitcnt vmcnt(0)" ::: "memory");
  __syncthreads();   // X ready; W(0) staged

  f32x4 pa[8];
  #pragma unroll
  for (int ct = 0; ct < 8; ++ct) pa[ct] = f32x4{0.f,0.f,0.f,0.f};

  for (int h = 0; h < 4; ++h){
    if (!WSOK){
      #pragma unroll
      for (int it = 0; it < 12; ++it){
        int e = tid + it*1024;
        int c = e & 127, t = e >> 7;
        int col = (t < 32) ? (h*32 + t) : (t < 64) ? (CC + h*32 + (t-32)) : (2*CC + h*32 + (t-64));
        *(u16*)(WTs + t*256 + ((((c>>3) ^ (t&7)))<<4) + (c&7)*2) = f2b(Wqkv[c*384 + col]);
      }
      #pragma unroll
      for (int it = 0; it < 4; ++it){
        int e = tid + it*1024;
        int d = e >> 7, o = e & 127;
        *(u16*)(WOs + (h&1)*10240 + (o*40 + d)*2) = (d < 32) ? f2b(Wo[(h*32 + d)*128 + o]) : (u16)0;
      }
      __syncthreads();
    }

    // ---- QKV GEMM: Q^T and V^T via W-as-A (swapped); K direct ----
    f32x4 qa[2], ka[2], va[2];
    #pragma unroll
    for (int dt = 0; dt < 2; ++dt)
      #pragma unroll
      for (int v = 0; v < 4; ++v){
        qa[dt][v] = BQs[h*32 + dt*16 + l4*4 + v];
        va[dt][v] = BQs[256 + h*32 + dt*16 + l4*4 + v];
      }
    {
      float bk0 = BQs[128 + h*32 + l15], bk1 = BQs[128 + h*32 + 16 + l15];
      ka[0] = f32x4{bk0,bk0,bk0,bk0}; ka[1] = f32x4{bk1,bk1,bk1,bk1};
    }
    #pragma unroll
    for (int ks = 0; ks < 4; ++ks){
      int swb = (((ks*4 + l4) ^ (l15 & 7)) << 4);
      short8 a0  = *(const short8*)(Xs  + (w*16 + l15)*256 + swb);
      short8 wq0 = *(const short8*)(WTs + (l15)*256 + swb);
      short8 wq1 = *(const short8*)(WTs + (16 + l15)*256 + swb);
      short8 wk0 = *(const short8*)(WTs + (32 + l15)*256 + swb);
      short8 wk1 = *(const short8*)(WTs + (48 + l15)*256 + swb);
      short8 wv0 = *(const short8*)(WTs + (64 + l15)*256 + swb);
      short8 wv1 = *(const short8*)(WTs + (80 + l15)*256 + swb);
      qa[0] = MFMA(wq0, a0, qa[0]); qa[1] = MFMA(wq1, a0, qa[1]);
      ka[0] = MFMA(a0, wk0, ka[0]); ka[1] = MFMA(a0, wk1, ka[1]);
      va[0] = MFMA(wv0, a0, va[0]); va[1] = MFMA(wv1, a0, va[1]);
    }
    short8 qf = redist(qa[0]*QSCL, qa[1]*QSCL, l4);
    #pragma unroll
    for (int kt = 0; kt < 2; ++kt)
      #pragma unroll
      for (int v = 0; v < 4; ++v)
        *(u16*)(KBs + ((w*16 + l4*4 + v)*40 + kt*16 + l15)*2) = (u16)cvtpk(ka[kt][v], ka[kt][v]);
    #pragma unroll
    for (int dt = 0; dt < 2; ++dt)
      #pragma unroll
      for (int v = 0; v < 4; ++v)
        *(u16*)(VTs + ((dt*16 + l4*4 + v)*264 + w*16 + l15)*2) = (u16)cvtpk(va[dt][v], va[dt][v]);
    __syncthreads();   // K/VT visible; all WT reads done

    if (WSOK && h < 3){  // prefetch next head's weights under the flash phase
      const char* wb = (const char*)wimg + (h+1)*34816;
      gload16(wb + tid*16, WTs + tid*16);
      if (tid < 512) gload16(wb + 16384 + tid*16, WTs + 16384 + tid*16);
      if (tid < 640) gload16(wb + 24576 + tid*16, WOs + ((h+1)&1)*10240 + tid*16);
    }

    __builtin_amdgcn_s_setprio(1);
    // ---- attention: full-row softmax in 2 halves of 128 keys ----
    float m = -3e38f, l = 0.f;
    f32x4 oacc0 = {0.f,0.f,0.f,0.f}, oacc1 = {0.f,0.f,0.f,0.f};
    #pragma unroll
    for (int hl = 0; hl < 2; ++hl){
      f32x4 sS[4][2];
      if (WSOK){
        // bias rides in as the MFMA C-operand (identical math, no post-add)
        const u16* bb = biasimg + qglob*256 + l4*64 + hl*32;
        #pragma unroll
        for (int ci = 0; ci < 4; ++ci){
          uint4 bw = *(const uint4*)(bb + ci*8);
          float c00,c01,c02,c03,c10,c11,c12,c13;
          unpk(bw.x, c00, c01); unpk(bw.y, c02, c03);
          unpk(bw.z, c10, c11); unpk(bw.w, c12, c13);
          f32x4 cb0 = {c00, c01, c02, c03};
          f32x4 cb1 = {c10, c11, c12, c13};
          int ch = hl*4 + ci;
          short8 kf0 = *(const short8*)(KBs + (ch*32 + l15)*80 + l4*16);
          short8 kf1 = *(const short8*)(KBs + (ch*32 + 16 + l15)*80 + l4*16);
          sS[ci][0] = MFMA(kf0, qf, cb0);
          sS[ci][1] = MFMA(kf1, qf, cb1);
        }
      } else {
        #pragma unroll
        for (int ci = 0; ci < 4; ++ci){
          int ch = hl*4 + ci;
          short8 kf0 = *(const short8*)(KBs + (ch*32 + l15)*80 + l4*16);
          short8 kf1 = *(const short8*)(KBs + (ch*32 + 16 + l15)*80 + l4*16);
          f32x4 z = {0.f,0.f,0.f,0.f};
          sS[ci][0] = MFMA(kf0, qf, z);
          sS[ci][1] = MFMA(kf1, qf, z);
        }
        #pragma unroll
        for (int ci = 0; ci < 4; ++ci)
          #pragma unroll
          for (int kt = 0; kt < 2; ++kt)
            #pragma unroll
            for (int v = 0; v < 4; ++v){
              int key = (hl*4 + ci)*32 + kt*16 + l4*4 + v;
              int mq = (PHASE==0) ? mask[qglob*NN + key] : mask[key*NN + qglob];
              sS[ci][kt][v] += mq ? NEGBIG : dsc*dist[qglob*NN + key];
            }
      }
      float mc0 = fmaxf(fmaxf(fmaxf(sS[0][0][0],sS[0][0][1]),fmaxf(sS[0][0][2],sS[0][0][3])),
                        fmaxf(fmaxf(sS[0][1][0],sS[0][1][1]),fmaxf(sS[0][1][2],sS[0][1][3])));
      float mc1 = fmaxf(fmaxf(fmaxf(sS[1][0][0],sS[1][0][1]),fmaxf(sS[1][0][2],sS[1][0][3])),
                        fmaxf(fmaxf(sS[1][1][0],sS[1][1][1]),fmaxf(sS[1][1][2],sS[1][1][3])));
      float mc2 = fmaxf(fmaxf(fmaxf(sS[2][0][0],sS[2][0][1]),fmaxf(sS[2][0][2],sS[2][0][3])),
                        fmaxf(fmaxf(sS[2][1][0],sS[2][1][1]),fmaxf(sS[2][1][2],sS[2][1][3])));
      float mc3 = fmaxf(fmaxf(fmaxf(sS[3][0][0],sS[3][0][1]),fmaxf(sS[3][0][2],sS[3][0][3])),
                        fmaxf(fmaxf(sS[3][1][0],sS[3][1][1]),fmaxf(sS[3][1][2],sS[3][1][3])));
      float mx = fmaxf(fmaxf(mc0,mc1), fmaxf(mc2,mc3));
      mx = fmaxf(mx, __shfl_xor(mx, 16));
      mx = fmaxf(mx, __shfl_xor(mx, 32));
      float mn = fmaxf(m, mx);
      float corr = EXP2(m - mn);
      m = mn;
      float ps = 0.f;
      #pragma unroll
      for (int ci = 0; ci < 4; ++ci){
        float p0=0.f, p1=0.f;
        #pragma unroll
        for (int v = 0; v < 4; ++v){
          sS[ci][0][v] = EXP2(sS[ci][0][v] - m); p0 += sS[ci][0][v];
          sS[ci][1][v] = EXP2(sS[ci][1][v] - m); p1 += sS[ci][1][v];
        }
        ps += p0 + p1;
      }
      ps += __shfl_xor(ps, 16);
      ps += __shfl_xor(ps, 32);
      l = l*corr + ps;
      oacc0 *= corr; oacc1 *= corr;
      #pragma unroll
      for (int ci = 0; ci < 4; ++ci){
        int ch = hl*4 + ci;
        short8 pf = redist(sS[ci][0], sS[ci][1], l4);
        short8 vt0 = *(const short8*)(VTs + (l15)*528 + ch*64 + l4*16);
        short8 vt1 = *(const short8*)(VTs + (16 + l15)*528 + ch*64 + l4*16);
        oacc0 = MFMA(vt0, pf, oacc0);
        oacc1 = MFMA(vt1, pf, oacc1);
      }
    }
    // ---- O normalize + in-reg redistribute + fuse O_h @ Wo_h ----
    {
      float inv = 1.f / l;
      short8 oA = redist(oacc0*inv, oacc1*inv, l4);
      const char* wob = WOs + (h&1)*10240;
      #pragma unroll
      for (int ct = 0; ct < 8; ++ct){
        short8 wB = *(const short8*)(wob + (ct*16 + l15)*80 + l4*16);
        pa[ct] = MFMA(oA, wB, pa[ct]);
      }
    }
    __builtin_amdgcn_s_setprio(0);
    if (WSOK && h < 3) asm volatile("s_waitcnt vmcnt(0)" ::: "memory");
    __syncthreads();   // flash reads of K/VT done; W(h+1) landed in all waves
  }

  // ---- epilogue: residual + bo + LN2 stats ----
  float mrs[4], mrq[4];
  #pragma unroll
  for (int v = 0; v < 4; ++v){ mrs[v] = 0.f; mrq[v] = 0.f; }
  #pragma unroll
  for (int ct = 0; ct < 8; ++ct)
    #pragma unroll
    for (int v = 0; v < 4; ++v){
      int o = ct*16 + l15;
      int r = w*16 + l4*4 + v;
      float xv = b2f(*(const u16*)(Xs + XBYTE(r, o)));
      float t = pa[ct][v] + GBs[256 + o] + xv;
      pa[ct][v] = t;
      mrs[v] += t; mrq[v] += t*t;
    }
  #pragma unroll
  for (int v = 0; v < 4; ++v){
    #pragma unroll
    for (int ms = 1; ms < 16; ms <<= 1){
      mrs[v] += __shfl_xor(mrs[v], ms);
      mrq[v] += __shfl_xor(mrq[v], ms);
    }
    float mean = mrs[v]*(1.f/CC);
    float var  = fmaxf(mrq[v]*(1.f/CC) - mean*mean, 0.f);
    mrs[v] = mean;
    mrq[v] = rsqrtf(var + EPSV);
  }
  // ---- coalesced write via wave-private LDS bounce (full 128B-line stores) ----
  // wave's slice of Xs (rows w*16..w*16+15 = 4KB) is private: LN wrote it, QKV/epilogue
  // read only own rows. Stage f32 [16][64] per half with swizzle c' = c ^ ((row>>2)<<4).
  {
    char* wbase = Xs + w*4096;
    const int r4 = l4;          // lid>>4
    const int cl = l15;
    #pragma unroll
    for (int half = 0; half < 2; ++half){
      #pragma unroll
      for (int ct4 = 0; ct4 < 4; ++ct4){
        int ct = half*4 + ct4;
        int o = ct*16 + l15;
        float gsc = GBs[o], gbi = GBs[128+o];
        #pragma unroll
        for (int v = 0; v < 4; ++v){
          float val = (pa[ct][v] - mrs[v])*mrq[v]*gsc + gbi;
          int row = l4*4 + v;
          int cw = (ct4*16 + l15) ^ (l4<<4);
          *(float*)(wbase + (row*64 + cw)*4) = val;
        }
      }
      asm volatile("s_waitcnt lgkmcnt(0)" ::: "memory");
      #pragma unroll
      for (int g = 0; g < 4; ++g){
        int row = g*4 + r4;
        int cb = (cl*4) ^ (g<<4);
        f32x4 vv = *(const f32x4*)(wbase + (row*64 + cb)*4);
        *(f32x4*)(orow + (w*16 + row)*CC + half*64 + cl*4) = vv;
      }
      asm volatile("s_waitcnt lgkmcnt(0)" ::: "memory");
    }
  }
}

// s_in[j][c] = sum_{k<j} pr[k][j][c]
__launch_bounds__(1024)
__global__ void colprefix_kernel(const float* __restrict__ pr, float* __restrict__ s_in){
  __shared__ float red[1024];
  int j = blockIdx.x;
  int c = threadIdx.x & 127, part = threadIdx.x >> 7;
  float a0 = 0.f, a1 = 0.f;
  for (int k = part; k < j; k += 16){
    a0 += pr[(size_t)k*NN*CC + j*CC + c];
    int k2 = k + 8;
    if (k2 < j) a1 += pr[(size_t)k2*NN*CC + j*CC + c];
  }
  red[threadIdx.x] = a0 + a1;
  __syncthreads();
  if (threadIdx.x < 128){
    float s = 0.f;
    #pragma unroll
    for (int p = 0; p < 8; ++p) s += red[p*128 + threadIdx.x];
    s_in[j*CC + threadIdx.x] = s;
  }
}

__launch_bounds__(128)
__global__ void single_kernel(const float* __restrict__ single,
                              const float* __restrict__ W1, const float* __restrict__ b1,
                              const float* __restrict__ W2, const float* __restrict__ b2,
                              const float* __restrict__ g, const float* __restrict__ bb,
                              float* __restrict__ sr){
  __shared__ float srow[128];
  __shared__ float sh1[256];
  __shared__ float red[4];
  int jr = blockIdx.x, t = threadIdx.x;
  srow[t] = single[jr*CC + t];
  __syncthreads();
  float a0 = b1[t], a1 = b1[t+128];
  for (int c = 0; c < 128; ++c){
    float s = srow[c];
    a0 += s * W1[c*256 + t];
    a1 += s * W1[c*256 + t + 128];
  }
  sh1[t] = fmaxf(a0, 0.f);
  sh1[t+128] = fmaxf(a1, 0.f);
  __syncthreads();
  float acc = b2[t];
  for (int o = 0; o < 256; ++o) acc += sh1[o] * W2[o*CC + t];
  acc = fmaxf(acc, 0.f);
  float tv = srow[t] + acc;
  float s = tv, q = tv*tv;
  #pragma unroll
  for (int mm = 32; mm; mm >>= 1){ s += __shfl_xor(s, mm); q += __shfl_xor(q, mm); }
  int w = t >> 6;
  if ((t & 63) == 0){ red[w] = s; red[2+w] = q; }
  __syncthreads();
  float S = red[0] + red[1], Q = red[2] + red[3];
  float mean = S*(1.f/CC);
  float var = fmaxf(Q*(1.f/CC) - mean*mean, 0.f);
  float rs = rsqrtf(var + EPSV);
  sr[jr*CC + t] = (tv - mean)*rs*g[t] + bb[t];
}

extern "C" void kernel_launch(void* const* d_in, const int* in_sizes, int n_in,
                              void* d_out, int out_size, void* d_ws, size_t ws_size,
                              hipStream_t stream) {
  const float* pair   = (const float*)d_in[0];
  const float* single = (const float*)d_in[1];
  const int*   mask   = (const int*)d_in[2];
  const float* dist   = (const float*)d_in[3];
  const float* rWqkv  = (const float*)d_in[4];
  const float* rbqkv  = (const float*)d_in[5];
  const float* rWo    = (const float*)d_in[6];
  const float* rbo    = (const float*)d_in[7];
  const float* rdsc   = (const float*)d_in[8];
  const float* cWqkv  = (const float*)d_in[9];
  const float* cbqkv  = (const float*)d_in[10];
  const float* cWo    = (const float*)d_in[11];
  const float* cbo    = (const float*)d_in[12];
  const float* cdsc   = (const float*)d_in[13];
  const float* pnr_g  = (const float*)d_in[14];
  const float* pnr_b  = (const float*)d_in[15];
  const float* pnc_g  = (const float*)d_in[16];
  const float* pnc_b  = (const float*)d_in[17];
  const float* sn_g   = (const float*)d_in[18];
  const float* sn_b   = (const float*)d_in[19];
  const float* W1     = (const float*)d_in[20];
  const float* b1     = (const float*)d_in[21];
  const float* W2     = (const float*)d_in[22];
  const float* b2     = (const float*)d_in[23];

  float* outp = (float*)d_out;
  float* pr   = outp;
  float* srr  = outp + (size_t)NN*NN*CC;

  const bool usews = ws_size >= (size_t)WS_NEED;
  char* wsb = (char*)d_ws;
  u16* bias0 = (u16*)(wsb + WS_B0);
  u16* bias1 = (u16*)(wsb + WS_B1);
  u16* wimg0 = (u16*)(wsb + WS_W0);
  u16* wimg1 = (u16*)(wsb + WS_W1);
  float* s_in = usews ? (float*)(wsb + WS_SIN) : srr;

  if (usews){
    (void)hipFuncSetAttribute(reinterpret_cast<const void*>(stage_kernel<0,1>),
                              hipFuncAttributeMaxDynamicSharedMemorySize, SMEM_BYTES);
    (void)hipFuncSetAttribute(reinterpret_cast<const void*>(stage_kernel<1,1>),
                              hipFuncAttributeMaxDynamicSharedMemorySize, SMEM_BYTES);
    single_kernel<<<NN, CC, 0, stream>>>(single, W1, b1, W2, b2, sn_g, sn_b, srr);
    prep_bias<<<NN, NN, 0, stream>>>(mask, dist, rdsc, cdsc, bias0, bias1);
    prep_wimg<<<8, 256, 0, stream>>>(rWqkv, rWo, cWqkv, cWo, wimg0, wimg1);
    stage_kernel<0,1><<<NN, 1024, SMEM_BYTES, stream>>>(pair, single, single, mask, dist,
        bias0, wimg0, rWqkv, rbqkv, rWo, rbo, rdsc, pnr_g, pnr_b, pr);
    colprefix_kernel<<<NN, 1024, 0, stream>>>(pr, s_in);
    stage_kernel<1,1><<<NN, 1024, SMEM_BYTES, stream>>>(pr, s_in, single, mask, dist,
        bias1, wimg1, cWqkv, cbqkv, cWo, cbo, cdsc, pnc_g, pnc_b, pr);
  } else {
    (void)hipFuncSetAttribute(reinterpret_cast<const void*>(stage_kernel<0,0>),
                              hipFuncAttributeMaxDynamicSharedMemorySize, SMEM_BYTES);
    (void)hipFuncSetAttribute(reinterpret_cast<const void*>(stage_kernel<1,0>),
                              hipFuncAttributeMaxDynamicSharedMemorySize, SMEM_BYTES);
    stage_kernel<0,0><<<NN, 1024, SMEM_BYTES, stream>>>(pair, single, single, mask, dist,
        nullptr, nullptr, rWqkv, rbqkv, rWo, rbo, rdsc, pnr_g, pnr_b, pr);
    colprefix_kernel<<<NN, 1024, 0, stream>>>(pr, s_in);
    stage_kernel<1,0><<<NN, 1024, SMEM_BYTES, stream>>>(pr, s_in, single, mask, dist,
        nullptr, nullptr, cWqkv, cbqkv, cWo, cbo, cdsc, pnc_g, pnc_b, pr);
    single_kernel<<<NN, CC, 0, stream>>>(single, W1, b1, W2, b2, sn_g, sn_b, srr);
  }
}

// Round 14
// 247.787 us; speedup vs baseline: 1.0708x; 1.0708x over previous
//
#include <hip/hip_runtime.h>
#include <math.h>

typedef unsigned int u32;
typedef unsigned short u16;
typedef __attribute__((ext_vector_type(8))) short short8;   // 8 bf16 in 4 VGPRs
typedef __attribute__((ext_vector_type(4))) float f32x4;
typedef __attribute__((ext_vector_type(2))) u32 u32x2;

#define NN 256
#define CC 128
#define EPSV 1e-5f
#define LOG2E 1.44269504088896f
#define QSCL (0.17677669529663687f * 1.44269504088896f)   // 1/sqrt(32) * log2(e)
#define NEGBIG -1e30f

#define MFMA(a,b,c) __builtin_amdgcn_mfma_f32_16x16x32_bf16(a,b,c,0,0,0)
#define EXP2(x) __builtin_amdgcn_exp2f(x)

__device__ __forceinline__ float b2f(u16 u){ return __uint_as_float(((u32)u)<<16); }
__device__ __forceinline__ u16 f2b(float f){
  u32 x = __float_as_uint(f);
  return (u16)((x + 0x7fffu + ((x>>16)&1u)) >> 16);
}
__device__ __forceinline__ void unpk(u32 u, float&a, float&b){
  a = __uint_as_float(u<<16); b = __uint_as_float(u & 0xffff0000u);
}
__device__ __forceinline__ u32 cvtpk(float lo, float hi){
  u32 r;
  asm("v_cvt_pk_bf16_f32 %0, %1, %2" : "=v"(r) : "v"(lo), "v"(hi));
  return r;
}
__device__ __forceinline__ void gload16(const void* g, void* l){
  __builtin_amdgcn_global_load_lds((const __attribute__((address_space(1))) u32*)g,
                                   (__attribute__((address_space(3))) u32*)l, 16, 0, 0);
}

// redistribute 8 values (2 f32x4 tiles, idx = tile*16 + l4*4 + v at col l15) into
// A/B-frag short8 (lane l4 gets idx l4*8..l4*8+7 for its l15). Verified P-path algebra.
__device__ __forceinline__ short8 redist(f32x4 t0, f32x4 t1, int l4){
  u32 A0 = cvtpk(t0[0], t0[1]), A1 = cvtpk(t0[2], t0[3]);
  u32 B0 = cvtpk(t1[0], t1[1]), B1 = cvtpk(t1[2], t1[3]);
  asm volatile("v_permlane32_swap_b32 %0, %1" : "+v"(A0), "+v"(B0));
  asm volatile("v_permlane32_swap_b32 %0, %1" : "+v"(A1), "+v"(B1));
  u32 sA0 = __shfl_xor(A0, 16), sA1 = __shfl_xor(A1, 16);
  u32 sB0 = __shfl_xor(B0, 16), sB1 = __shfl_xor(B1, 16);
  bool eg = ((l4 & 1) == 0);
  union { u32 u[4]; short8 s; } pu;
  pu.u[0] = eg ? A0 : sB0;
  pu.u[1] = eg ? A1 : sB1;
  pu.u[2] = eg ? sA0 : B0;
  pu.u[3] = eg ? sA1 : B1;
  return pu.s;
}

// ---- LDS layout (bytes) ----
#define XS_OFF   0        // bf16 X[256][128] swizzled                  (65536)
#define WT_OFF   65536    // bf16 Wt[96][128] head slice, swizzled      (24576)
#define WO_OFF   90112    // bf16 Woh dbuf [2][128][40]                 (20480)
#define KB_OFF   110592   // bf16 K[256][40]                            (20480)
#define VT_OFF   131072   // bf16 Vt[32][264]                           (16896)
#define SV_OFF   147968   // f32 sv[128]                                (512)
#define GB_OFF   148480   // f32 g[128], b[128], bo[128]                (1536)
#define BQ_OFF   150016   // f32 bqkv[384]                              (1536)
#define RS_OFF   151552   // f32 red[16][128] (phase-0 scratch)         (8192)
#define SMEM_BYTES 159744

#define XBYTE(r,c) ((r)*256 + (((((c)>>3)) ^ ((r)&7))<<4) + ((c)&7)*2)

// ws layout (bytes)
#define WS_B0   0          // bias img phase0 (131072)
#define WS_B1   131072     // bias img phase1 (131072)
#define WS_W0   262144     // W img stage0 (139264 = 4 heads x (24576 WT + 10240 WO))
#define WS_W1   401408     // W img stage1 (139264)
#define WS_SIN  540672     // s_in f32 (131072)
#define WS_NEED 671744

// merged prep: blocks 0..255 = bias image, 256..263 = weight images, 264..519 = single path
__launch_bounds__(256)
__global__ void prep_all(const int* __restrict__ mask, const float* __restrict__ dist,
                         const float* __restrict__ rd, const float* __restrict__ cd,
                         u16* __restrict__ bimg0, u16* __restrict__ bimg1,
                         const float* __restrict__ rWqkv, const float* __restrict__ rWo,
                         const float* __restrict__ cWqkv, const float* __restrict__ cWo,
                         u16* __restrict__ img0, u16* __restrict__ img1,
                         const float* __restrict__ single,
                         const float* __restrict__ W1, const float* __restrict__ b1v,
                         const float* __restrict__ W2, const float* __restrict__ b2v,
                         const float* __restrict__ sg, const float* __restrict__ sb,
                         float* __restrict__ sr){
  int blk = blockIdx.x;
  if (blk < 256){
    // bias image, per-lane-consumed layout: u16 addr = q*256 + l4*64 + ch*8 + kt*4 + v
    int q = blk, k = threadIdx.x;
    int l4 = (k >> 2) & 3, v = k & 3, kt = (k >> 4) & 1, ch = k >> 5;
    int addr = q*256 + l4*64 + ch*8 + kt*4 + v;
    float dv = dist[q*NN + k];
    bimg0[addr] = mask[q*NN + k] ? f2b(NEGBIG) : f2b(rd[0]*LOG2E*dv);
    bimg1[addr] = mask[k*NN + q] ? f2b(NEGBIG) : f2b(cd[0]*LOG2E*dv);
  } else if (blk < 264){
    int h = (blk - 256) & 3, s = (blk - 256) >> 2;
    const float* Wq = s ? cWqkv : rWqkv;
    const float* Wom = s ? cWo : rWo;
    char* base = (char*)(s ? img1 : img0) + h*34816;
    for (int e = threadIdx.x; e < 96*128; e += 256){
      int t = e >> 7, c = e & 127;
      int col = (t < 32) ? (h*32 + t) : (t < 64) ? (CC + h*32 + (t-32)) : (2*CC + h*32 + (t-64));
      *(u16*)(base + t*256 + ((((c>>3) ^ (t&7)))<<4) + (c&7)*2) = f2b(Wq[c*384 + col]);
    }
    for (int e = threadIdx.x; e < 128*40; e += 256){
      int o = e / 40, d = e - o*40;
      *(u16*)(base + 24576 + (o*40 + d)*2) = (d < 32) ? f2b(Wom[(h*32 + d)*128 + o]) : (u16)0;
    }
  } else {
    // single path on first 128 threads; all 256 hit the same __syncthreads
    __shared__ float srow[128];
    __shared__ float sh1[256];
    __shared__ float red[4];
    int jr = blk - 264, t = threadIdx.x;
    bool act = t < 128;
    int tt = act ? t : 0;
    if (act) srow[t] = single[jr*CC + t];
    __syncthreads();
    float a0 = b1v[tt], a1 = b1v[tt+128];
    for (int c = 0; c < 128; ++c){
      float s = srow[c];
      a0 += s * W1[c*256 + tt];
      a1 += s * W1[c*256 + tt + 128];
    }
    if (act){ sh1[t] = fmaxf(a0, 0.f); sh1[t+128] = fmaxf(a1, 0.f); }
    __syncthreads();
    float acc = b2v[tt];
    for (int o = 0; o < 256; ++o) acc += sh1[o] * W2[o*CC + tt];
    acc = fmaxf(acc, 0.f);
    float tv = srow[tt] + acc;
    float s = tv, q = tv*tv;
    #pragma unroll
    for (int mm = 32; mm; mm >>= 1){ s += __shfl_xor(s, mm); q += __shfl_xor(q, mm); }
    int w = t >> 6;
    if ((t & 63) == 0 && act){ red[w] = s; red[2+w] = q; }
    __syncthreads();
    float S = red[0] + red[1], Q = red[2] + red[3];
    float mean = S*(1.f/CC);
    float var = fmaxf(Q*(1.f/CC) - mean*mean, 0.f);
    float rs = rsqrtf(var + EPSV);
    if (act) sr[jr*CC + t] = (tv - mean)*rs*sg[t] + sb[t];
  }
}

// standalone fallbacks (non-ws path)
__global__ void prep_bias(const int* __restrict__ mask, const float* __restrict__ dist,
                          const float* __restrict__ rd, const float* __restrict__ cd,
                          u16* __restrict__ b0, u16* __restrict__ b1){
  int q = blockIdx.x, k = threadIdx.x;
  int l4 = (k >> 2) & 3, v = k & 3, kt = (k >> 4) & 1, ch = k >> 5;
  int addr = q*256 + l4*64 + ch*8 + kt*4 + v;
  float dv = dist[q*NN + k];
  b0[addr] = mask[q*NN + k] ? f2b(NEGBIG) : f2b(rd[0]*LOG2E*dv);
  b1[addr] = mask[k*NN + q] ? f2b(NEGBIG) : f2b(cd[0]*LOG2E*dv);
}

template<int PHASE, int WSOK>
__launch_bounds__(1024)
__global__ void stage_kernel(const float* __restrict__ pin, const float* __restrict__ colmat,
                             const float* __restrict__ singlerow,
                             const int* __restrict__ mask, const float* __restrict__ dist,
                             const u16* __restrict__ biasimg,
                             const u16* __restrict__ wimg,
                             const float* __restrict__ Wqkv, const float* __restrict__ bqkv,
                             const float* __restrict__ Wo, const float* __restrict__ bo,
                             const float* __restrict__ dscale,
                             const float* __restrict__ lng, const float* __restrict__ lnb,
                             float* __restrict__ outp)
{
  extern __shared__ char smem[];
  char* Xs  = smem + XS_OFF;
  char* WTs = smem + WT_OFF;
  char* WOs = smem + WO_OFF;
  char* KBs = smem + KB_OFF;
  char* VTs = smem + VT_OFF;
  float* SVs = (float*)(smem + SV_OFF);
  float* GBs = (float*)(smem + GB_OFF);
  float* BQs = (float*)(smem + BQ_OFF);
  float* RSs = (float*)(smem + RS_OFF);

  const int i = blockIdx.x;
  const int tid = threadIdx.x;
  const int lid = tid & 63;
  const int w = tid >> 6;            // 16 waves; wave owns query rows w*16..w*16+15
  const int l15 = lid & 15;
  const int l4  = lid >> 4;
  const int h32 = lid >> 5;
  const int c4  = (lid & 31) * 4;
  const float* prow = pin + (size_t)i*NN*CC;
  float* orow = outp + (size_t)i*NN*CC;
  const int qglob = w*16 + l15;
  const float dsc = dscale[0] * LOG2E;

  // issue W(head 0) staging immediately (lands during LN phase)
  if (WSOK){
    const char* wb = (const char*)wimg;
    gload16(wb + tid*16, WTs + tid*16);
    if (tid < 512) gload16(wb + 16384 + tid*16, WTs + 16384 + tid*16);
    if (tid < 640) gload16(wb + 24576 + tid*16, WOs + tid*16);
  }
  if (tid < 128){ GBs[tid] = lng[tid]; GBs[128+tid] = lnb[tid]; GBs[256+tid] = bo[tid]; }
  if (tid >= 512 && tid < 896) BQs[tid-512] = bqkv[tid-512];

  // ---- LN1 -> X (bf16 swizzled); phase 0 fuses the s_out prefix ----
  if (PHASE == 0){
    f32x4 svp = {0.f,0.f,0.f,0.f};
    #pragma unroll 4
    for (int p = 0; p < 8; ++p){
      int r = w*16 + p*2 + h32;
      f32x4 pr4 = *(const f32x4*)(prow + r*CC + c4);
      f32x4 sg4 = *(const f32x4*)(colmat + r*CC + c4);
      f32x4 t = pr4 + sg4;
      u32x2 pk2; pk2.x = cvtpk(t[0], t[1]); pk2.y = cvtpk(t[2], t[3]);
      *(u32x2*)(Xs + XBYTE(r, c4)) = pk2;
      if (r < i) svp += pr4;
    }
    #pragma unroll
    for (int q = 0; q < 4; ++q) svp[q] += __shfl_xor(svp[q], 32);
    if (h32 == 0) *(f32x4*)(RSs + w*128 + c4) = svp;
    __syncthreads();
    if (tid < 128){
      float s = 0.f;
      #pragma unroll
      for (int ww = 0; ww < 16; ++ww) s += RSs[ww*128 + tid];
      SVs[tid] = s;
    }
    __syncthreads();
    f32x4 sv4 = *(const f32x4*)(SVs + c4);
    f32x4 g4  = *(const f32x4*)(GBs + c4);
    f32x4 b4  = *(const f32x4*)(GBs + 128 + c4);
    #pragma unroll 2
    for (int p = 0; p < 8; ++p){
      int r = w*16 + p*2 + h32;
      u32x2 st = *(const u32x2*)(Xs + XBYTE(r, c4));
      float t0,t1,t2,t3;
      unpk(st.x, t0, t1); unpk(st.y, t2, t3);
      t0 += sv4[0]; t1 += sv4[1]; t2 += sv4[2]; t3 += sv4[3];
      float s = (t0+t1)+(t2+t3);
      float q2 = (t0*t0+t1*t1)+(t2*t2+t3*t3);
      #pragma unroll
      for (int ms = 1; ms < 32; ms <<= 1){ s += __shfl_xor(s, ms); q2 += __shfl_xor(q2, ms); }
      float mean = s*(1.f/CC);
      float var  = fmaxf(q2*(1.f/CC) - mean*mean, 0.f);
      float rstd = rsqrtf(var + EPSV);
      float y0 = (t0-mean)*rstd*g4[0] + b4[0];
      float y1 = (t1-mean)*rstd*g4[1] + b4[1];
      float y2 = (t2-mean)*rstd*g4[2] + b4[2];
      float y3 = (t3-mean)*rstd*g4[3] + b4[3];
      u32x2 pk2; pk2.x = cvtpk(y0, y1); pk2.y = cvtpk(y2, y3);
      *(u32x2*)(Xs + XBYTE(r, c4)) = pk2;
    }
  } else {
    if (tid < 128) SVs[tid] = singlerow[i*CC + tid];
    __syncthreads();
    f32x4 sv4 = *(const f32x4*)(SVs + c4);
    f32x4 g4  = *(const f32x4*)(GBs + c4);
    f32x4 b4  = *(const f32x4*)(GBs + 128 + c4);
    #pragma unroll 4
    for (int p = 0; p < 8; ++p){
      int r = w*16 + p*2 + h32;
      f32x4 pr4 = *(const f32x4*)(prow + r*CC + c4);
      f32x4 cm4 = *(const f32x4*)(colmat + r*CC + c4);
      float t0 = pr4[0]+cm4[0]+sv4[0], t1 = pr4[1]+cm4[1]+sv4[1];
      float t2 = pr4[2]+cm4[2]+sv4[2], t3 = pr4[3]+cm4[3]+sv4[3];
      float s = (t0+t1)+(t2+t3);
      float q2 = (t0*t0+t1*t1)+(t2*t2+t3*t3);
      #pragma unroll
      for (int ms = 1; ms < 32; ms <<= 1){ s += __shfl_xor(s, ms); q2 += __shfl_xor(q2, ms); }
      float mean = s*(1.f/CC);
      float var  = fmaxf(q2*(1.f/CC) - mean*mean, 0.f);
      float rstd = rsqrtf(var + EPSV);
      float y0 = (t0-mean)*rstd*g4[0] + b4[0];
      float y1 = (t1-mean)*rstd*g4[1] + b4[1];
      float y2 = (t2-mean)*rstd*g4[2] + b4[2];
      float y3 = (t3-mean)*rstd*g4[3] + b4[3];
      u32x2 pk2; pk2.x = cvtpk(y0, y1); pk2.y = cvtpk(y2, y3);
      *(u32x2*)(Xs + XBYTE(r, c4)) = pk2;
    }
  }
  if (WSOK) asm volatile("s_waitcnt vmcnt(0)" ::: "memory");
  __syncthreads();   // X ready; W(0) staged

  f32x4 pa[8];
  #pragma unroll
  for (int ct = 0; ct < 8; ++ct) pa[ct] = f32x4{0.f,0.f,0.f,0.f};

  for (int h = 0; h < 4; ++h){
    if (!WSOK){
      #pragma unroll
      for (int it = 0; it < 12; ++it){
        int e = tid + it*1024;
        int c = e & 127, t = e >> 7;
        int col = (t < 32) ? (h*32 + t) : (t < 64) ? (CC + h*32 + (t-32)) : (2*CC + h*32 + (t-64));
        *(u16*)(WTs + t*256 + ((((c>>3) ^ (t&7)))<<4) + (c&7)*2) = f2b(Wqkv[c*384 + col]);
      }
      #pragma unroll
      for (int it = 0; it < 4; ++it){
        int e = tid + it*1024;
        int d = e >> 7, o = e & 127;
        *(u16*)(WOs + (h&1)*10240 + (o*40 + d)*2) = (d < 32) ? f2b(Wo[(h*32 + d)*128 + o]) : (u16)0;
      }
      __syncthreads();
    }

    // ---- QKV GEMM: Q^T and V^T via W-as-A (swapped); K direct ----
    f32x4 qa[2], ka[2], va[2];
    #pragma unroll
    for (int dt = 0; dt < 2; ++dt)
      #pragma unroll
      for (int v = 0; v < 4; ++v){
        qa[dt][v] = BQs[h*32 + dt*16 + l4*4 + v];
        va[dt][v] = BQs[256 + h*32 + dt*16 + l4*4 + v];
      }
    {
      float bk0 = BQs[128 + h*32 + l15], bk1 = BQs[128 + h*32 + 16 + l15];
      ka[0] = f32x4{bk0,bk0,bk0,bk0}; ka[1] = f32x4{bk1,bk1,bk1,bk1};
    }
    #pragma unroll
    for (int ks = 0; ks < 4; ++ks){
      int swb = (((ks*4 + l4) ^ (l15 & 7)) << 4);
      short8 a0  = *(const short8*)(Xs  + (w*16 + l15)*256 + swb);
      short8 wq0 = *(const short8*)(WTs + (l15)*256 + swb);
      short8 wq1 = *(const short8*)(WTs + (16 + l15)*256 + swb);
      short8 wk0 = *(const short8*)(WTs + (32 + l15)*256 + swb);
      short8 wk1 = *(const short8*)(WTs + (48 + l15)*256 + swb);
      short8 wv0 = *(const short8*)(WTs + (64 + l15)*256 + swb);
      short8 wv1 = *(const short8*)(WTs + (80 + l15)*256 + swb);
      qa[0] = MFMA(wq0, a0, qa[0]); qa[1] = MFMA(wq1, a0, qa[1]);
      ka[0] = MFMA(a0, wk0, ka[0]); ka[1] = MFMA(a0, wk1, ka[1]);
      va[0] = MFMA(wv0, a0, va[0]); va[1] = MFMA(wv1, a0, va[1]);
    }
    short8 qf = redist(qa[0]*QSCL, qa[1]*QSCL, l4);
    #pragma unroll
    for (int kt = 0; kt < 2; ++kt)
      #pragma unroll
      for (int v = 0; v < 4; ++v)
        *(u16*)(KBs + ((w*16 + l4*4 + v)*40 + kt*16 + l15)*2) = (u16)cvtpk(ka[kt][v], ka[kt][v]);
    #pragma unroll
    for (int dt = 0; dt < 2; ++dt)
      #pragma unroll
      for (int v = 0; v < 4; ++v)
        *(u16*)(VTs + ((dt*16 + l4*4 + v)*264 + w*16 + l15)*2) = (u16)cvtpk(va[dt][v], va[dt][v]);
    __syncthreads();   // K/VT visible; all WT reads done

    if (WSOK && h < 3){  // prefetch next head's weights under the flash phase
      const char* wb = (const char*)wimg + (h+1)*34816;
      gload16(wb + tid*16, WTs + tid*16);
      if (tid < 512) gload16(wb + 16384 + tid*16, WTs + 16384 + tid*16);
      if (tid < 640) gload16(wb + 24576 + tid*16, WOs + ((h+1)&1)*10240 + tid*16);
    }

    __builtin_amdgcn_s_setprio(1);
    // ---- attention: full-row softmax in 2 halves of 128 keys ----
    float m = -3e38f, l = 0.f;
    f32x4 oacc0 = {0.f,0.f,0.f,0.f}, oacc1 = {0.f,0.f,0.f,0.f};
    #pragma unroll
    for (int hl = 0; hl < 2; ++hl){
      f32x4 sS[4][2];
      if (WSOK){
        // bias rides in as the MFMA C-operand (identical math, no post-add)
        const u16* bb = biasimg + qglob*256 + l4*64 + hl*32;
        #pragma unroll
        for (int ci = 0; ci < 4; ++ci){
          uint4 bw = *(const uint4*)(bb + ci*8);
          float c00,c01,c02,c03,c10,c11,c12,c13;
          unpk(bw.x, c00, c01); unpk(bw.y, c02, c03);
          unpk(bw.z, c10, c11); unpk(bw.w, c12, c13);
          f32x4 cb0 = {c00, c01, c02, c03};
          f32x4 cb1 = {c10, c11, c12, c13};
          int ch = hl*4 + ci;
          short8 kf0 = *(const short8*)(KBs + (ch*32 + l15)*80 + l4*16);
          short8 kf1 = *(const short8*)(KBs + (ch*32 + 16 + l15)*80 + l4*16);
          sS[ci][0] = MFMA(kf0, qf, cb0);
          sS[ci][1] = MFMA(kf1, qf, cb1);
        }
      } else {
        #pragma unroll
        for (int ci = 0; ci < 4; ++ci){
          int ch = hl*4 + ci;
          short8 kf0 = *(const short8*)(KBs + (ch*32 + l15)*80 + l4*16);
          short8 kf1 = *(const short8*)(KBs + (ch*32 + 16 + l15)*80 + l4*16);
          f32x4 z = {0.f,0.f,0.f,0.f};
          sS[ci][0] = MFMA(kf0, qf, z);
          sS[ci][1] = MFMA(kf1, qf, z);
        }
        #pragma unroll
        for (int ci = 0; ci < 4; ++ci)
          #pragma unroll
          for (int kt = 0; kt < 2; ++kt)
            #pragma unroll
            for (int v = 0; v < 4; ++v){
              int key = (hl*4 + ci)*32 + kt*16 + l4*4 + v;
              int mq = (PHASE==0) ? mask[qglob*NN + key] : mask[key*NN + qglob];
              sS[ci][kt][v] += mq ? NEGBIG : dsc*dist[qglob*NN + key];
            }
      }
      float mc0 = fmaxf(fmaxf(fmaxf(sS[0][0][0],sS[0][0][1]),fmaxf(sS[0][0][2],sS[0][0][3])),
                        fmaxf(fmaxf(sS[0][1][0],sS[0][1][1]),fmaxf(sS[0][1][2],sS[0][1][3])));
      float mc1 = fmaxf(fmaxf(fmaxf(sS[1][0][0],sS[1][0][1]),fmaxf(sS[1][0][2],sS[1][0][3])),
                        fmaxf(fmaxf(sS[1][1][0],sS[1][1][1]),fmaxf(sS[1][1][2],sS[1][1][3])));
      float mc2 = fmaxf(fmaxf(fmaxf(sS[2][0][0],sS[2][0][1]),fmaxf(sS[2][0][2],sS[2][0][3])),
                        fmaxf(fmaxf(sS[2][1][0],sS[2][1][1]),fmaxf(sS[2][1][2],sS[2][1][3])));
      float mc3 = fmaxf(fmaxf(fmaxf(sS[3][0][0],sS[3][0][1]),fmaxf(sS[3][0][2],sS[3][0][3])),
                        fmaxf(fmaxf(sS[3][1][0],sS[3][1][1]),fmaxf(sS[3][1][2],sS[3][1][3])));
      float mx = fmaxf(fmaxf(mc0,mc1), fmaxf(mc2,mc3));
      mx = fmaxf(mx, __shfl_xor(mx, 16));
      mx = fmaxf(mx, __shfl_xor(mx, 32));
      float mn = fmaxf(m, mx);
      float corr = EXP2(m - mn);
      m = mn;
      float ps = 0.f;
      #pragma unroll
      for (int ci = 0; ci < 4; ++ci){
        float p0=0.f, p1=0.f;
        #pragma unroll
        for (int v = 0; v < 4; ++v){
          sS[ci][0][v] = EXP2(sS[ci][0][v] - m); p0 += sS[ci][0][v];
          sS[ci][1][v] = EXP2(sS[ci][1][v] - m); p1 += sS[ci][1][v];
        }
        ps += p0 + p1;
      }
      ps += __shfl_xor(ps, 16);
      ps += __shfl_xor(ps, 32);
      l = l*corr + ps;
      oacc0 *= corr; oacc1 *= corr;
      #pragma unroll
      for (int ci = 0; ci < 4; ++ci){
        int ch = hl*4 + ci;
        short8 pf = redist(sS[ci][0], sS[ci][1], l4);
        short8 vt0 = *(const short8*)(VTs + (l15)*528 + ch*64 + l4*16);
        short8 vt1 = *(const short8*)(VTs + (16 + l15)*528 + ch*64 + l4*16);
        oacc0 = MFMA(vt0, pf, oacc0);
        oacc1 = MFMA(vt1, pf, oacc1);
      }
    }
    // ---- O normalize + in-reg redistribute + fuse O_h @ Wo_h ----
    {
      float inv = 1.f / l;
      short8 oA = redist(oacc0*inv, oacc1*inv, l4);
      const char* wob = WOs + (h&1)*10240;
      #pragma unroll
      for (int ct = 0; ct < 8; ++ct){
        short8 wB = *(const short8*)(wob + (ct*16 + l15)*80 + l4*16);
        pa[ct] = MFMA(oA, wB, pa[ct]);
      }
    }
    __builtin_amdgcn_s_setprio(0);
    if (WSOK && h < 3) asm volatile("s_waitcnt vmcnt(0)" ::: "memory");
    __syncthreads();   // flash reads of K/VT done; W(h+1) landed in all waves
  }

  // ---- epilogue: residual + bo + LN2 + plain coalesced write ----
  float mrs[4], mrq[4];
  #pragma unroll
  for (int v = 0; v < 4; ++v){ mrs[v] = 0.f; mrq[v] = 0.f; }
  #pragma unroll
  for (int ct = 0; ct < 8; ++ct)
    #pragma unroll
    for (int v = 0; v < 4; ++v){
      int o = ct*16 + l15;
      int r = w*16 + l4*4 + v;
      float xv = b2f(*(const u16*)(Xs + XBYTE(r, o)));
      float t = pa[ct][v] + GBs[256 + o] + xv;
      pa[ct][v] = t;
      mrs[v] += t; mrq[v] += t*t;
    }
  #pragma unroll
  for (int v = 0; v < 4; ++v){
    #pragma unroll
    for (int ms = 1; ms < 16; ms <<= 1){
      mrs[v] += __shfl_xor(mrs[v], ms);
      mrq[v] += __shfl_xor(mrq[v], ms);
    }
    float mean = mrs[v]*(1.f/CC);
    float var  = fmaxf(mrq[v]*(1.f/CC) - mean*mean, 0.f);
    mrs[v] = mean;
    mrq[v] = rsqrtf(var + EPSV);
  }
  #pragma unroll
  for (int ct = 0; ct < 8; ++ct)
    #pragma unroll
    for (int v = 0; v < 4; ++v){
      int o = ct*16 + l15;
      int r = w*16 + l4*4 + v;
      orow[r*CC + o] = (pa[ct][v] - mrs[v])*mrq[v]*GBs[o] + GBs[128+o];
    }
}

// s_in[j][c] = sum_{k<j} pr[k][j][c]
__launch_bounds__(1024)
__global__ void colprefix_kernel(const float* __restrict__ pr, float* __restrict__ s_in){
  __shared__ float red[1024];
  int j = blockIdx.x;
  int c = threadIdx.x & 127, part = threadIdx.x >> 7;
  float a0 = 0.f, a1 = 0.f;
  for (int k = part; k < j; k += 16){
    a0 += pr[(size_t)k*NN*CC + j*CC + c];
    int k2 = k + 8;
    if (k2 < j) a1 += pr[(size_t)k2*NN*CC + j*CC + c];
  }
  red[threadIdx.x] = a0 + a1;
  __syncthreads();
  if (threadIdx.x < 128){
    float s = 0.f;
    #pragma unroll
    for (int p = 0; p < 8; ++p) s += red[p*128 + threadIdx.x];
    s_in[j*CC + threadIdx.x] = s;
  }
}

__launch_bounds__(128)
__global__ void single_kernel(const float* __restrict__ single,
                              const float* __restrict__ W1, const float* __restrict__ b1,
                              const float* __restrict__ W2, const float* __restrict__ b2,
                              const float* __restrict__ g, const float* __restrict__ bb,
                              float* __restrict__ sr){
  __shared__ float srow[128];
  __shared__ float sh1[256];
  __shared__ float red[4];
  int jr = blockIdx.x, t = threadIdx.x;
  srow[t] = single[jr*CC + t];
  __syncthreads();
  float a0 = b1[t], a1 = b1[t+128];
  for (int c = 0; c < 128; ++c){
    float s = srow[c];
    a0 += s * W1[c*256 + t];
    a1 += s * W1[c*256 + t + 128];
  }
  sh1[t] = fmaxf(a0, 0.f);
  sh1[t+128] = fmaxf(a1, 0.f);
  __syncthreads();
  float acc = b2[t];
  for (int o = 0; o < 256; ++o) acc += sh1[o] * W2[o*CC + t];
  acc = fmaxf(acc, 0.f);
  float tv = srow[t] + acc;
  float s = tv, q = tv*tv;
  #pragma unroll
  for (int mm = 32; mm; mm >>= 1){ s += __shfl_xor(s, mm); q += __shfl_xor(q, mm); }
  int w = t >> 6;
  if ((t & 63) == 0){ red[w] = s; red[2+w] = q; }
  __syncthreads();
  float S = red[0] + red[1], Q = red[2] + red[3];
  float mean = S*(1.f/CC);
  float var = fmaxf(Q*(1.f/CC) - mean*mean, 0.f);
  float rs = rsqrtf(var + EPSV);
  sr[jr*CC + t] = (tv - mean)*rs*g[t] + bb[t];
}

extern "C" void kernel_launch(void* const* d_in, const int* in_sizes, int n_in,
                              void* d_out, int out_size, void* d_ws, size_t ws_size,
                              hipStream_t stream) {
  const float* pair   = (const float*)d_in[0];
  const float* single = (const float*)d_in[1];
  const int*   mask   = (const int*)d_in[2];
  const float* dist   = (const float*)d_in[3];
  const float* rWqkv  = (const float*)d_in[4];
  const float* rbqkv  = (const float*)d_in[5];
  const float* rWo    = (const float*)d_in[6];
  const float* rbo    = (const float*)d_in[7];
  const float* rdsc   = (const float*)d_in[8];
  const float* cWqkv  = (const float*)d_in[9];
  const float* cbqkv  = (const float*)d_in[10];
  const float* cWo    = (const float*)d_in[11];
  const float* cbo    = (const float*)d_in[12];
  const float* cdsc   = (const float*)d_in[13];
  const float* pnr_g  = (const float*)d_in[14];
  const float* pnr_b  = (const float*)d_in[15];
  const float* pnc_g  = (const float*)d_in[16];
  const float* pnc_b  = (const float*)d_in[17];
  const float* sn_g   = (const float*)d_in[18];
  const float* sn_b   = (const float*)d_in[19];
  const float* W1     = (const float*)d_in[20];
  const float* b1     = (const float*)d_in[21];
  const float* W2     = (const float*)d_in[22];
  const float* b2     = (const float*)d_in[23];

  float* outp = (float*)d_out;
  float* pr   = outp;
  float* srr  = outp + (size_t)NN*NN*CC;

  const bool usews = ws_size >= (size_t)WS_NEED;
  char* wsb = (char*)d_ws;
  u16* bias0 = (u16*)(wsb + WS_B0);
  u16* bias1 = (u16*)(wsb + WS_B1);
  u16* wimg0 = (u16*)(wsb + WS_W0);
  u16* wimg1 = (u16*)(wsb + WS_W1);
  float* s_in = usews ? (float*)(wsb + WS_SIN) : srr;

  if (usews){
    (void)hipFuncSetAttribute(reinterpret_cast<const void*>(stage_kernel<0,1>),
                              hipFuncAttributeMaxDynamicSharedMemorySize, SMEM_BYTES);
    (void)hipFuncSetAttribute(reinterpret_cast<const void*>(stage_kernel<1,1>),
                              hipFuncAttributeMaxDynamicSharedMemorySize, SMEM_BYTES);
    prep_all<<<520, 256, 0, stream>>>(mask, dist, rdsc, cdsc, bias0, bias1,
        rWqkv, rWo, cWqkv, cWo, wimg0, wimg1,
        single, W1, b1, W2, b2, sn_g, sn_b, srr);
    stage_kernel<0,1><<<NN, 1024, SMEM_BYTES, stream>>>(pair, single, single, mask, dist,
        bias0, wimg0, rWqkv, rbqkv, rWo, rbo, rdsc, pnr_g, pnr_b, pr);
    colprefix_kernel<<<NN, 1024, 0, stream>>>(pr, s_in);
    stage_kernel<1,1><<<NN, 1024, SMEM_BYTES, stream>>>(pr, s_in, single, mask, dist,
        bias1, wimg1, cWqkv, cbqkv, cWo, cbo, cdsc, pnc_g, pnc_b, pr);
  } else {
    (void)hipFuncSetAttribute(reinterpret_cast<const void*>(stage_kernel<0,0>),
                              hipFuncAttributeMaxDynamicSharedMemorySize, SMEM_BYTES);
    (void)hipFuncSetAttribute(reinterpret_cast<const void*>(stage_kernel<1,0>),
                              hipFuncAttributeMaxDynamicSharedMemorySize, SMEM_BYTES);
    stage_kernel<0,0><<<NN, 1024, SMEM_BYTES, stream>>>(pair, single, single, mask, dist,
        nullptr, nullptr, rWqkv, rbqkv, rWo, rbo, rdsc, pnr_g, pnr_b, pr);
    colprefix_kernel<<<NN, 1024, 0, stream>>>(pr, s_in);
    stage_kernel<1,0><<<NN, 1024, SMEM_BYTES, stream>>>(pr, s_in, single, mask, dist,
        nullptr, nullptr, cWqkv, cbqkv, cWo, cbo, cdsc, pnc_g, pnc_b, pr);
    single_kernel<<<NN, CC, 0, stream>>>(single, W1, b1, W2, b2, sn_g, sn_b, srr);
  }
}